// Round 4
// baseline (453.879 us; speedup 1.0000x reference)
//
#include <hip/hip_runtime.h>
#include <hip/hip_bf16.h>
#include <stdint.h>

#define D_MODEL 512
#define NH 8
#define DH 64
#define BB 2
#define SS 4096
#define MTOT (BB*SS)   // 8192

typedef __attribute__((ext_vector_type(8))) short bf16x8;
typedef __attribute__((ext_vector_type(4))) short bf16x4;
typedef __attribute__((ext_vector_type(4))) float f32x4;

#if __has_builtin(__builtin_amdgcn_mfma_f32_16x16x16_bf16)
  #define MFMA16(a,b,c) __builtin_amdgcn_mfma_f32_16x16x16_bf16(a,b,c,0,0,0)
#else
  #define MFMA16(a,b,c) __builtin_amdgcn_mfma_f32_16x16x16bf16_1k(a,b,c,0,0,0)
#endif
#define MFMA32(a,b,c) __builtin_amdgcn_mfma_f32_16x16x32_bf16(a,b,c,0,0,0)

__device__ __forceinline__ unsigned f2b(float f) {
  unsigned u = __float_as_uint(f);
  u += 0x7FFF + ((u >> 16) & 1);   // RNE (finite inputs only)
  return u >> 16;
}

__device__ __forceinline__ uint4 pack8(float4 a, float4 b) {
  uint4 r;
  r.x = f2b(a.x) | (f2b(a.y) << 16);
  r.y = f2b(a.z) | (f2b(a.w) << 16);
  r.z = f2b(b.x) | (f2b(b.y) << 16);
  r.w = f2b(b.z) | (f2b(b.w) << 16);
  return r;
}

// ---------------- GEMM: C[m][n] = sum_k A[m][k]*W[n][k] + bias[n] ----------------
// W: [512,512] fp32 row-major (B^T layout), cast to bf16 during staging.
// mode 0: A fp32.  z<2 : bf16 out[((b*NH+h)*SS+s)*DH+dh]   (Q,K head layout)
//                  z==2: bf16 out[((b*NH+h)*DH+dh)*SS+s]   (V TRANSPOSED per head)
// mode 1: A bf16 (Ao). fp32 outf[m*512+n]                  (final output)
struct GemmArgs {
  const void* A[3];
  const float* W[3];
  const float* bias[3];
  unsigned short* out[3];
  float* outf;
  int mode;
};

__global__ __launch_bounds__(256) void gemm_kernel(GemmArgs g) {
  const int z = blockIdx.z;
  const float* __restrict__ bias = g.bias[z];
  unsigned short* __restrict__ out = g.out[z];
  const bool vt = (g.mode == 0) && (z == 2);

  __shared__ __align__(16) unsigned short lA[128][40];  // 32 cols + 8 pad
  __shared__ __align__(16) unsigned short lB[128][40];

  const int t = threadIdx.x;
  const int lane = t & 63;
  const int w = t >> 6;
  const int wr = w >> 1, wc = w & 1;
  const int lrow = lane & 15, quad = lane >> 4;
  const int m0 = blockIdx.y * 128;
  const int n0 = blockIdx.x * 128;

  f32x4 acc[4][4];
  for (int i = 0; i < 4; i++)
    for (int j = 0; j < 4; j++)
      for (int r = 0; r < 4; r++) acc[i][j][r] = 0.f;

  for (int kk = 0; kk < 512; kk += 32) {
#pragma unroll
    for (int i = 0; i < 2; i++) {
      int id = t + i * 256;          // 0..511
      int row = id >> 2;             // 0..127
      int c8 = (id & 3) * 8;         // 0,8,16,24
      if (g.mode == 0) {
        const float* Af = (const float*)g.A[z];
        float4 a0 = *(const float4*)(Af + (size_t)(m0 + row) * 512 + kk + c8);
        float4 a1 = *(const float4*)(Af + (size_t)(m0 + row) * 512 + kk + c8 + 4);
        *(uint4*)&lA[row][c8] = pack8(a0, a1);
      } else {
        const unsigned short* Ab = (const unsigned short*)g.A[z];
        *(uint4*)&lA[row][c8] = *(const uint4*)(Ab + (size_t)(m0 + row) * 512 + kk + c8);
      }
      const float* Wf = g.W[z];
      float4 w0 = *(const float4*)(Wf + (size_t)(n0 + row) * 512 + kk + c8);
      float4 w1 = *(const float4*)(Wf + (size_t)(n0 + row) * 512 + kk + c8 + 4);
      *(uint4*)&lB[row][c8] = pack8(w0, w1);
    }
    __syncthreads();
    bf16x8 af[4], bfr[4];
#pragma unroll
    for (int mt = 0; mt < 4; mt++) af[mt] = *(const bf16x8*)&lA[wr * 64 + mt * 16 + lrow][quad * 8];
#pragma unroll
    for (int nt = 0; nt < 4; nt++) bfr[nt] = *(const bf16x8*)&lB[wc * 64 + nt * 16 + lrow][quad * 8];
#pragma unroll
    for (int mt = 0; mt < 4; mt++)
#pragma unroll
      for (int nt = 0; nt < 4; nt++)
        acc[mt][nt] = MFMA32(af[mt], bfr[nt], acc[mt][nt]);
    __syncthreads();
  }

  float bv[4];
#pragma unroll
  for (int nt = 0; nt < 4; nt++) bv[nt] = bias[n0 + wc * 64 + nt * 16 + lrow];

#pragma unroll
  for (int mt = 0; mt < 4; mt++) {
#pragma unroll
    for (int nt = 0; nt < 4; nt++) {
      const int n = n0 + wc * 64 + nt * 16 + lrow;
      const int mB = m0 + wr * 64 + mt * 16 + quad * 4;   // r=0 row
      float val[4];
#pragma unroll
      for (int r = 0; r < 4; r++) val[r] = acc[mt][nt][r] + bv[nt];

      if (g.mode == 1) {
#pragma unroll
        for (int r = 0; r < 4; r++) g.outf[(size_t)(mB + r) * 512 + n] = val[r];
      } else if (vt) {
        // V transposed: [b,h][dh][s]; r-consecutive rows = contiguous s
        const int bb = mB >> 12, s = mB & 4095;
        const int hh = n >> 6, dh = n & 63;
        ushort4 pk = make_ushort4((unsigned short)f2b(val[0]), (unsigned short)f2b(val[1]),
                                  (unsigned short)f2b(val[2]), (unsigned short)f2b(val[3]));
        *(ushort4*)(out + (((size_t)bb * NH + hh) * DH + dh) * SS + s) = pk;
      } else {
        const int bb = mB >> 12;
        const int hh = n >> 6, dh = n & 63;
#pragma unroll
        for (int r = 0; r < 4; r++) {
          const int s = (mB + r) & 4095;
          out[((((size_t)bb * NH + hh) * SS + s) << 6) + dh] = (unsigned short)f2b(val[r]);
        }
      }
    }
  }
}

// ---------------- flash attention, S^T formulation ----------------
// grid (SS/64=64, NH, BB) = 1024 blocks, 128 threads (2 waves), 64 Q-rows/block.
// Wave w owns j-tiles jt = w, w+2, ... (32-wide each), staged in wave-PRIVATE LDS
// (no barriers in main loop). S^T = K*Q^T so P^T's MFMA C-layout registers are
// directly a valid K=16 B-operand for O^T = V^T * P^T — no LDS round-trip for P.
__global__ __launch_bounds__(128, 2) void attn_kernel(const unsigned short* __restrict__ Qh,
                                                      const unsigned short* __restrict__ Kh,
                                                      const unsigned short* __restrict__ Vt,
                                                      unsigned short* __restrict__ Ao) {
  // per-wave region: lK[32][72] (4608B) + lV[64][40] (5120B) = 9728B; 2 waves = 19456B
  // reduction reuse: red[64][68] f32 (17408B) + lred[64] f32 (256B)
  __shared__ __align__(16) unsigned char smem[19968];

  const int t = threadIdx.x;
  const int lane = t & 63;
  const int w = t >> 6;
  const int lrow = lane & 15, quad = lane >> 4;
  const int h = blockIdx.y, b = blockIdx.z;
  const size_t kb = ((size_t)b * NH + h) * SS * DH;   // Q,K base: [s][dh]
  const size_t vb = ((size_t)b * NH + h) * DH * SS;   // Vt base: [dh][s]
  const int qrow0 = blockIdx.x * 64;

  unsigned short* lKw = (unsigned short*)(smem + w * 9728);
  unsigned short* lVw = (unsigned short*)(smem + w * 9728 + 4608);

  // Q as B-operand frags (identical register layout to an A-frag load):
  // qf[ti][c] holds Q[i=ti*16+lrow][d = c*32 + quad*8 + 0..7]
  bf16x8 qf[4][2];
#pragma unroll
  for (int ti = 0; ti < 4; ti++) {
    const unsigned short* qp = Qh + kb + (size_t)(qrow0 + ti * 16 + lrow) * DH + quad * 8;
    qf[ti][0] = *(const bf16x8*)qp;
    qf[ti][1] = *(const bf16x8*)(qp + 32);
  }

  bf16x4 ones;
#pragma unroll
  for (int i = 0; i < 4; i++) ones[i] = (short)0x3F80;

  // O^T accumulators: o[ti][nt] lane reg r = O[i=ti*16+lrow][d = nt*16+quad*4+r]
  f32x4 o[4][4], lac[4];
#pragma unroll
  for (int ti = 0; ti < 4; ti++) {
    for (int nt = 0; nt < 4; nt++)
      for (int r = 0; r < 4; r++) o[ti][nt][r] = 0.f;
    for (int r = 0; r < 4; r++) lac[ti][r] = 0.f;
  }

  uint4 kreg[4], vreg[4];
  {
    const int jb = w * 32;
#pragma unroll
    for (int p = 0; p < 4; p++) {
      const int cid = p * 64 + lane;
      kreg[p] = *(const uint4*)(Kh + kb + (size_t)(jb + (cid >> 3)) * DH + (cid & 7) * 8);
      vreg[p] = *(const uint4*)(Vt + vb + (size_t)(cid >> 2) * SS + jb + (cid & 3) * 8);
    }
  }

  for (int jt = w; jt < SS / 32; jt += 2) {
    // stage current tile (wave-private; DS ops are in-order per wave)
#pragma unroll
    for (int p = 0; p < 4; p++) {
      const int cid = p * 64 + lane;
      *(uint4*)&lKw[(cid >> 3) * 72 + (cid & 7) * 8] = kreg[p];
      *(uint4*)&lVw[(cid >> 2) * 40 + (cid & 3) * 8] = vreg[p];
    }
    // prefetch next tile into registers (overlaps compute below)
    {
      const int nj = jt + 2;
      const int jb2 = (nj < SS / 32 ? nj : jt) * 32;
#pragma unroll
      for (int p = 0; p < 4; p++) {
        const int cid = p * 64 + lane;
        kreg[p] = *(const uint4*)(Kh + kb + (size_t)(jb2 + (cid >> 3)) * DH + (cid & 7) * 8);
        vreg[p] = *(const uint4*)(Vt + vb + (size_t)(cid >> 2) * SS + jb2 + (cid & 3) * 8);
      }
    }

    // S^T = K * Q^T  (A = K frag, B = Q frag). C-layout: row=j=quad*4+r(+16ntj),
    // col=i=lrow(+16ti). Then p = exp(s/8 - 8) packed to bf16x4 (j-order = r).
    bf16x4 pf[2][4];
#pragma unroll
    for (int ntj = 0; ntj < 2; ntj++) {
      bf16x8 k0 = *(const bf16x8*)&lKw[(ntj * 16 + lrow) * 72 + quad * 8];
      bf16x8 k1 = *(const bf16x8*)&lKw[(ntj * 16 + lrow) * 72 + 32 + quad * 8];
#pragma unroll
      for (int ti = 0; ti < 4; ti++) {
        f32x4 s;
        for (int r = 0; r < 4; r++) s[r] = 0.f;
        s = MFMA32(k0, qf[ti][0], s);
        s = MFMA32(k1, qf[ti][1], s);
        bf16x4 pk;
#pragma unroll
        for (int r = 0; r < 4; r++)
          pk[r] = (short)f2b(__expf(fmaf(s[r], 0.125f, -8.0f)));
        pf[ntj][ti] = pk;
      }
    }

    // O^T += V^T * P^T ; l += 1 * P^T   (K=16 MFMAs, P straight from registers)
#pragma unroll
    for (int ks = 0; ks < 2; ks++) {
#pragma unroll
      for (int ti = 0; ti < 4; ti++)
        lac[ti] = MFMA16(ones, pf[ks][ti], lac[ti]);
#pragma unroll
      for (int nt = 0; nt < 4; nt++) {
        bf16x4 vf = *(const bf16x4*)&lVw[(nt * 16 + lrow) * 40 + ks * 16 + quad * 4];
#pragma unroll
        for (int ti = 0; ti < 4; ti++)
          o[ti][nt] = MFMA16(vf, pf[ks][ti], o[ti][nt]);
      }
    }
  }

  // cross-wave reduction (first barriers in the kernel)
  __syncthreads();
  float* red = (float*)smem;            // [64][68]
  float* lred = (float*)(smem + 17408); // [64]
  if (w == 1) {
#pragma unroll
    for (int ti = 0; ti < 4; ti++) {
#pragma unroll
      for (int nt = 0; nt < 4; nt++)
        *(f32x4*)&red[(ti * 16 + lrow) * 68 + nt * 16 + quad * 4] = o[ti][nt];
      if (quad == 0) lred[ti * 16 + lrow] = lac[ti][0];
    }
  }
  __syncthreads();
  if (w == 0) {
#pragma unroll
    for (int ti = 0; ti < 4; ti++) {
      const float lt = lac[ti][0] + lred[ti * 16 + lrow];
      const float inv = __builtin_amdgcn_rcpf(lt);
      const int s = qrow0 + ti * 16 + lrow;
      unsigned short* dst = Ao + ((size_t)(b * SS + s)) * D_MODEL + h * DH;
#pragma unroll
      for (int nt = 0; nt < 4; nt++) {
        f32x4 sum = o[ti][nt];
        f32x4 part = *(const f32x4*)&red[(ti * 16 + lrow) * 68 + nt * 16 + quad * 4];
        ushort4 pk = make_ushort4((unsigned short)f2b((sum[0] + part[0]) * inv),
                                  (unsigned short)f2b((sum[1] + part[1]) * inv),
                                  (unsigned short)f2b((sum[2] + part[2]) * inv),
                                  (unsigned short)f2b((sum[3] + part[3]) * inv));
        *(ushort4*)(dst + nt * 16 + quad * 4) = pk;
      }
    }
  }
}

// ---------------- launch ----------------
extern "C" void kernel_launch(void* const* d_in, const int* in_sizes, int n_in,
                              void* d_out, int out_size, void* d_ws, size_t ws_size,
                              hipStream_t stream) {
  const float* q  = (const float*)d_in[0];
  const float* k  = (const float*)d_in[1];
  const float* v  = (const float*)d_in[2];
  const float* Wq = (const float*)d_in[3];
  const float* bq = (const float*)d_in[4];
  const float* Wk = (const float*)d_in[5];
  const float* bk = (const float*)d_in[6];
  const float* Wv = (const float*)d_in[7];
  const float* bv = (const float*)d_in[8];
  const float* Wo = (const float*)d_in[9];
  const float* bo = (const float*)d_in[10];

  const size_t NX = (size_t)MTOT * D_MODEL;     // 4,194,304

  char* p = (char*)d_ws;
  unsigned short* Qh  = (unsigned short*)p; p += NX * 2;
  unsigned short* Kh  = (unsigned short*)p; p += NX * 2;
  unsigned short* Vtg = (unsigned short*)p; p += NX * 2;
  unsigned short* Ao  = (unsigned short*)p; p += NX * 2;

  GemmArgs pa;
  pa.A[0] = q; pa.A[1] = k; pa.A[2] = v;
  pa.W[0] = Wq; pa.W[1] = Wk; pa.W[2] = Wv;
  pa.bias[0] = bq; pa.bias[1] = bk; pa.bias[2] = bv;
  pa.out[0] = Qh; pa.out[1] = Kh; pa.out[2] = Vtg;
  pa.outf = nullptr;
  pa.mode = 0;
  gemm_kernel<<<dim3(4, 64, 3), 256, 0, stream>>>(pa);

  attn_kernel<<<dim3(SS / 64, NH, BB), 128, 0, stream>>>(Qh, Kh, Vtg, Ao);

  GemmArgs oa;
  oa.A[0] = Ao; oa.A[1] = Ao; oa.A[2] = Ao;
  oa.W[0] = Wo; oa.W[1] = Wo; oa.W[2] = Wo;
  oa.bias[0] = bo; oa.bias[1] = bo; oa.bias[2] = bo;
  oa.out[0] = nullptr; oa.out[1] = nullptr; oa.out[2] = nullptr;
  oa.outf = (float*)d_out;
  oa.mode = 1;
  gemm_kernel<<<dim3(4, 64, 1), 256, 0, stream>>>(oa);
}